// Round 5
// baseline (365.914 us; speedup 1.0000x reference)
//
#include <hip/hip_runtime.h>
#include <hip/hip_bf16.h>
#include <math.h>

#define NB 8192
#define NG 8
#define NK 1024
#define ND 64
#define GD 512
#define MARGIN 2.5e-4f

typedef __attribute__((ext_vector_type(8))) short short8;
typedef __attribute__((ext_vector_type(4))) float f32x4;

// ws BYTE layout
#define WS_C2_OFF    0                      // f32[8192]        32KB
#define WS_CBH_OFF   32768                  // bf16[8*1024*64]  1MB
#define WS_CBL_OFF   (32768 + 1048576)      // bf16[8*1024*64]  1MB
#define WS_CAND_OFF  (32768 + 2097152)      // f32x4[65536]     1MB
#define WS_HIST_OFF  (32768 + 3145728)      // u32[1024]
#define WS_PART_OFF  (32768 + 3145728 + 4096) // f32[16384]

__device__ inline void bsplit(float v, short& hs, short& ls) {
    __hip_bfloat16 h = __float2bfloat16(v);
    float hf = __bfloat162float(h);
    __hip_bfloat16 l = __float2bfloat16(v - hf);
    hs = *reinterpret_cast<short*>(&h);
    ls = *reinterpret_cast<short*>(&l);
}

__device__ inline float wredsum(float v) {
#pragma unroll
    for (int st = 1; st < 64; st <<= 1) v += __shfl_xor(v, st);
    return v;
}

// ---------------- prep: c2, bf16 hi/lo codebook, hist zero ----------------
__global__ __launch_bounds__(256) void vq_prep(const float* __restrict__ cb,
                                               float* __restrict__ ws) {
    const int gid = blockIdx.x * 256 + threadIdx.x;            // 0..8191
    const float* c = cb + (size_t)gid * ND;
    ushort* cbh = (ushort*)((char*)ws + WS_CBH_OFF) + (size_t)gid * ND;
    ushort* cbl = (ushort*)((char*)ws + WS_CBL_OFF) + (size_t)gid * ND;

    float a0 = 0.f, a1 = 0.f, a2 = 0.f, a3 = 0.f;
#pragma unroll
    for (int i = 0; i < ND / 4; ++i) {
        const float4 v = reinterpret_cast<const float4*>(c)[i];
        a0 = fmaf(v.x, v.x, a0);
        a1 = fmaf(v.y, v.y, a1);
        a2 = fmaf(v.z, v.z, a2);
        a3 = fmaf(v.w, v.w, a3);
        short h0, l0, h1, l1, h2, l2, h3, l3;
        bsplit(v.x, h0, l0); bsplit(v.y, h1, l1);
        bsplit(v.z, h2, l2); bsplit(v.w, h3, l3);
        ushort4 hv, lv;
        hv.x = (ushort)h0; hv.y = (ushort)h1; hv.z = (ushort)h2; hv.w = (ushort)h3;
        lv.x = (ushort)l0; lv.y = (ushort)l1; lv.z = (ushort)l2; lv.w = (ushort)l3;
        reinterpret_cast<ushort4*>(cbh)[i] = hv;
        reinterpret_cast<ushort4*>(cbl)[i] = lv;
    }
    ((float*)((char*)ws + WS_C2_OFF))[gid] = (a0 + a1) + (a2 + a3);
    if (gid < NK) ((unsigned*)((char*)ws + WS_HIST_OFF))[gid] = 0u;
}

// ---- score: MFMA bf16 3-split, m=1, 4 waves/SIMD, depth-2 B prefetch,
// ----        round-3 float argmin (bit-identical numerics to the passing kernel)
__global__ __launch_bounds__(256, 4) void vq_score(const float* __restrict__ z,
                                                   float* __restrict__ ws) {
    const int tid  = threadIdx.x;
    const int w    = tid >> 6;
    const int lane = tid & 63;
    const int lo   = lane & 15, hi = lane >> 4;
    const int g    = blockIdx.y;
    const int rbase = blockIdx.x * 64 + w * 16;

    const ushort* cbh = (const ushort*)((const char*)ws + WS_CBH_OFF) + (size_t)g * NK * ND;
    const ushort* cbl = (const ushort*)((const char*)ws + WS_CBL_OFF) + (size_t)g * NK * ND;
    const float*  c2g = (const float*)((const char*)ws + WS_C2_OFF) + g * NK;

    // A fragments (16 z-rows), bf16 hi/lo split. row=lo, d=ks*32+hi*8+e
    short8 Ah[2], Al[2];
#pragma unroll
    for (int ks = 0; ks < 2; ++ks) {
        const float* zp = z + (size_t)(rbase + lo) * GD + g * ND + ks * 32 + hi * 8;
        float vv[8];
        *reinterpret_cast<float4*>(&vv[0]) = reinterpret_cast<const float4*>(zp)[0];
        *reinterpret_cast<float4*>(&vv[4]) = reinterpret_cast<const float4*>(zp)[1];
#pragma unroll
        for (int e = 0; e < 8; ++e) {
            short hs, ls;
            bsplit(vv[e], hs, ls);
            Ah[ks][e] = hs;
            Al[ks][e] = ls;
        }
    }

    // round-3 style per-q streams: (best, b2, bk, k2) as floats/ints
    float best[4], b2[4];
    int   bk[4], k2[4];
#pragma unroll
    for (int q = 0; q < 4; ++q) { best[q] = 3.0e38f; b2[q] = 3.0e38f; bk[q] = 0; k2[q] = 0; }

    const int laneoff = lo * 64 + hi * 8;   // shorts; code-row stride is 64 shorts

    // rotating 2-slot B-pair register buffer; pair p = ks*4 + n, slot = p&1
    short8 bh[2], bl[2];
    bh[0] = *reinterpret_cast<const short8*>(cbh + laneoff);          // (it0,p0)
    bl[0] = *reinterpret_cast<const short8*>(cbl + laneoff);
    bh[1] = *reinterpret_cast<const short8*>(cbh + 1024 + laneoff);   // (it0,p1)
    bl[1] = *reinterpret_cast<const short8*>(cbl + 1024 + laneoff);

#pragma unroll
    for (int it = 0; it < 16; ++it) {
        const int kb = it * 64;
        float c2v[4];
#pragma unroll
        for (int n = 0; n < 4; ++n) c2v[n] = c2g[kb + n * 16 + lo];

        f32x4 acc[4] = {{0.f,0.f,0.f,0.f},{0.f,0.f,0.f,0.f},{0.f,0.f,0.f,0.f},{0.f,0.f,0.f,0.f}};
#pragma unroll
        for (int p = 0; p < 8; ++p) {
            const int ks = p >> 2, n = p & 3;
            const int sl = p & 1;
            acc[n] = __builtin_amdgcn_mfma_f32_16x16x32_bf16(Ah[ks], bh[sl], acc[n], 0, 0, 0);
            acc[n] = __builtin_amdgcn_mfma_f32_16x16x32_bf16(Ah[ks], bl[sl], acc[n], 0, 0, 0);
            acc[n] = __builtin_amdgcn_mfma_f32_16x16x32_bf16(Al[ks], bh[sl], acc[n], 0, 0, 0);
            const int s = it * 8 + p + 2;            // prefetch pair s into freed slot
            if (s < 128) {
                const int itn = s >> 3, pn = s & 7;
                const size_t noff = (size_t)itn * 4096 + (size_t)(pn & 3) * 1024
                                  + (size_t)(pn >> 2) * 32 + laneoff;
                bh[sl] = *reinterpret_cast<const short8*>(cbh + noff);
                bl[sl] = *reinterpret_cast<const short8*>(cbl + noff);
            }
        }

        // epilogue: score = c2 - 2*zc (z2 constant per row); round-3 arithmetic
#pragma unroll
        for (int n = 0; n < 4; ++n) {
            const int kv = kb + n * 16 + lo;
#pragma unroll
            for (int q = 0; q < 4; ++q) {
                const float s = fmaf(-2.0f, acc[n][q], c2v[n]);
                const bool lt  = s < best[q];
                const bool lt2 = s < b2[q];
                b2[q]   = lt ? best[q] : (lt2 ? s : b2[q]);
                k2[q]   = lt ? bk[q]   : (lt2 ? kv : k2[q]);
                best[q] = lt ? s : best[q];
                bk[q]   = lt ? kv : bk[q];
            }
        }
    }

    // butterfly over the 16 lo-lanes (round-3 verbatim, m folded out)
    f32x4* cand = (f32x4*)((char*)ws + WS_CAND_OFF);
#pragma unroll
    for (int q = 0; q < 4; ++q) {
        float pb = best[q], p2 = b2[q];
        int   kq = bk[q],   kq2 = k2[q];
#pragma unroll
        for (int st = 1; st < 16; st <<= 1) {
            const float ob  = __shfl_xor(pb, st);
            const int   obk = __shfl_xor(kq, st);
            const float ob2 = __shfl_xor(p2, st);
            const int   ok2 = __shfl_xor(kq2, st);
            const bool bet = (ob < pb) || (ob == pb && obk < kq);
            const float lb  = bet ? pb : ob;      // loser's best
            const int   lk  = bet ? kq : obk;
            const float wb2 = bet ? ob2 : p2;     // winner's second
            const int   wk2 = bet ? ok2 : kq2;
            const bool s2 = (lb < wb2) || (lb == wb2 && lk < wk2);
            p2  = s2 ? lb : wb2;
            kq2 = s2 ? lk : wk2;
            pb  = bet ? ob : pb;
            kq  = bet ? obk : kq;
        }

        if (lo == 0) {
            const int row = rbase + hi * 4 + q;
            f32x4 c;
            c[0] = pb;
            c[1] = __int_as_float(kq);
            c[2] = p2;
            c[3] = __int_as_float(kq2);
            cand[(size_t)g * NB + row] = c;
        }
    }
}

// ---------------- pick: round-3 window-2 exact rescue, write outputs ----------------
__global__ __launch_bounds__(256) void vq_pick(const float* __restrict__ z,
                                               const float* __restrict__ cb,
                                               float* __restrict__ out,
                                               float* __restrict__ ws) {
    const int tid  = threadIdx.x;
    const int wid  = tid >> 6;
    const int lane = tid & 63;
    const int unit = blockIdx.x * 4 + wid;     // 0..65535
    const int row  = unit >> 3;
    const int g    = unit & 7;

    const f32x4* cand = (const f32x4*)((const char*)ws + WS_CAND_OFF);
    const f32x4 cd = cand[(size_t)g * NB + row];
    const float bapp = cd[0];
    const int   bk   = __float_as_int(cd[1]);

    const float zd = z[(size_t)row * GD + g * ND + lane];
    int win = bk;

    if (cd[2] - bapp <= MARGIN) {              // wave-uniform rescue branch
        const int kalt = __float_as_int(cd[3]);
        const float* cgrp = cb + (size_t)g * NK * ND;
        const float* c2g  = (const float*)((const char*)ws + WS_C2_OFF) + g * NK;
        const float z2 = wredsum(zd * zd);
        const float c1 = cgrp[(size_t)bk * ND + lane];
        const float d1 = (z2 + c2g[bk]) - 2.0f * wredsum(zd * c1);
        const float c2 = cgrp[(size_t)kalt * ND + lane];
        const float d2 = (z2 + c2g[kalt]) - 2.0f * wredsum(zd * c2);
        if (d2 < d1 || (d2 == d1 && kalt < bk)) win = kalt;
    }

    const float cw = cb[((size_t)g * NK + win) * ND + lane];
    out[(size_t)row * GD + g * ND + lane] = zd + (cw - zd);

    const float e  = zd - cw;
    const float cs = wredsum(e * e);

    __shared__ float sh[4];
    if (lane == 0) {
        out[(size_t)NB * GD + (size_t)row * NG + g] = (float)win;
        atomicAdd((unsigned*)((char*)ws + WS_HIST_OFF) + win, 1u);
        sh[wid] = cs;
    }
    __syncthreads();
    if (tid == 0)
        ((float*)((char*)ws + WS_PART_OFF))[blockIdx.x] = (sh[0] + sh[1]) + (sh[2] + sh[3]);
}

// ---------------- finalize ----------------
__global__ __launch_bounds__(1024) void vq_final(const float* __restrict__ ws,
                                                 float* __restrict__ out) {
    const int t = threadIdx.x;
    __shared__ float se[1024];
    __shared__ float sc[1024];
    const unsigned cnt = ((const unsigned*)((const char*)ws + WS_HIST_OFF))[t];
    const float usage = (float)cnt * (1.0f / 65536.f);
    se[t] = -usage * logf(usage + 1e-10f);
    const float* part = (const float*)((const char*)ws + WS_PART_OFF);
    float s = 0.f;
#pragma unroll
    for (int i = 0; i < 16; ++i) s += part[t * 16 + i];
    sc[t] = s;
    __syncthreads();
    for (int st = 512; st > 0; st >>= 1) {
        if (t < st) {
            se[t] += se[t + st];
            sc[t] += sc[t + st];
        }
        __syncthreads();
    }
    if (t == 0) {
        float* scal = out + (size_t)NB * GD + (size_t)NB * NG;
        scal[0] = sc[0] * (1.0f / ((float)NB * NG * ND));  // commitment_loss
        scal[1] = 0.0f;                                    // codebook_loss
        scal[2] = se[0];                                   // entropy
        scal[3] = expf(se[0]);                             // perplexity
    }
}

extern "C" void kernel_launch(void* const* d_in, const int* in_sizes, int n_in,
                              void* d_out, int out_size, void* d_ws, size_t ws_size,
                              hipStream_t stream) {
    const float* z  = (const float*)d_in[0];
    const float* cb = (const float*)d_in[1];
    float* out = (float*)d_out;
    float* ws  = (float*)d_ws;

    hipLaunchKernelGGL(vq_prep,  dim3(32),     dim3(256),  0, stream, cb, ws);
    hipLaunchKernelGGL(vq_score, dim3(128, 8), dim3(256),  0, stream, z, ws);
    hipLaunchKernelGGL(vq_pick,  dim3(16384),  dim3(256),  0, stream, z, cb, out, ws);
    hipLaunchKernelGGL(vq_final, dim3(1),      dim3(1024), 0, stream, ws, out);
}

// Round 6
// 161.158 us; speedup vs baseline: 2.2705x; 2.2705x over previous
//
#include <hip/hip_runtime.h>
#include <hip/hip_bf16.h>
#include <math.h>

#define NB 8192
#define NG 8
#define NK 1024
#define ND 64
#define GD 512
#define MARGIN 2.5e-4f

typedef __attribute__((ext_vector_type(8))) short short8;
typedef __attribute__((ext_vector_type(4))) float f32x4;

// ws BYTE layout
#define WS_C2_OFF    0                      // f32[8192]        32KB
#define WS_CBH_OFF   32768                  // bf16[8*1024*64]  1MB
#define WS_CBL_OFF   (32768 + 1048576)      // bf16[8*1024*64]  1MB
#define WS_CAND_OFF  (32768 + 2097152)      // f32x4[65536]     1MB
#define WS_HIST_OFF  (32768 + 3145728)      // u32[1024]
#define WS_PART_OFF  (32768 + 3145728 + 4096) // f32[16384]

__device__ inline void bsplit(float v, short& hs, short& ls) {
    __hip_bfloat16 h = __float2bfloat16(v);
    float hf = __bfloat162float(h);
    __hip_bfloat16 l = __float2bfloat16(v - hf);
    hs = *reinterpret_cast<short*>(&h);
    ls = *reinterpret_cast<short*>(&l);
}

__device__ inline float wredsum(float v) {
#pragma unroll
    for (int st = 1; st < 64; st <<= 1) v += __shfl_xor(v, st);
    return v;
}

// ---------------- prep: c2, bf16 hi/lo codebook, hist zero ----------------
__global__ __launch_bounds__(256) void vq_prep(const float* __restrict__ cb,
                                               float* __restrict__ ws) {
    const int gid = blockIdx.x * 256 + threadIdx.x;            // 0..8191
    const float* c = cb + (size_t)gid * ND;
    ushort* cbh = (ushort*)((char*)ws + WS_CBH_OFF) + (size_t)gid * ND;
    ushort* cbl = (ushort*)((char*)ws + WS_CBL_OFF) + (size_t)gid * ND;

    float a0 = 0.f, a1 = 0.f, a2 = 0.f, a3 = 0.f;
#pragma unroll
    for (int i = 0; i < ND / 4; ++i) {
        const float4 v = reinterpret_cast<const float4*>(c)[i];
        a0 = fmaf(v.x, v.x, a0);
        a1 = fmaf(v.y, v.y, a1);
        a2 = fmaf(v.z, v.z, a2);
        a3 = fmaf(v.w, v.w, a3);
        short h0, l0, h1, l1, h2, l2, h3, l3;
        bsplit(v.x, h0, l0); bsplit(v.y, h1, l1);
        bsplit(v.z, h2, l2); bsplit(v.w, h3, l3);
        ushort4 hv, lv;
        hv.x = (ushort)h0; hv.y = (ushort)h1; hv.z = (ushort)h2; hv.w = (ushort)h3;
        lv.x = (ushort)l0; lv.y = (ushort)l1; lv.z = (ushort)l2; lv.w = (ushort)l3;
        reinterpret_cast<ushort4*>(cbh)[i] = hv;
        reinterpret_cast<ushort4*>(cbl)[i] = lv;
    }
    ((float*)((char*)ws + WS_C2_OFF))[gid] = (a0 + a1) + (a2 + a3);
    if (gid < NK) ((unsigned*)((char*)ws + WS_HIST_OFF))[gid] = 0u;
}

// ---- score: MFMA bf16 3-split, m=1, 4 waves/SIMD, depth-2 B prefetch,
// ----        it-loop NOT unrolled (unroll-1) to keep live ranges short: no spill
__global__ __launch_bounds__(256, 4) void vq_score(const float* __restrict__ z,
                                                   float* __restrict__ ws) {
    const int tid  = threadIdx.x;
    const int w    = tid >> 6;
    const int lane = tid & 63;
    const int lo   = lane & 15, hi = lane >> 4;
    const int g    = blockIdx.y;
    const int rbase = blockIdx.x * 64 + w * 16;

    const ushort* cbh = (const ushort*)((const char*)ws + WS_CBH_OFF) + (size_t)g * NK * ND;
    const ushort* cbl = (const ushort*)((const char*)ws + WS_CBL_OFF) + (size_t)g * NK * ND;
    const float*  c2g = (const float*)((const char*)ws + WS_C2_OFF) + g * NK;

    // A fragments (16 z-rows), bf16 hi/lo split. row=lo, d=ks*32+hi*8+e
    short8 Ah[2], Al[2];
#pragma unroll
    for (int ks = 0; ks < 2; ++ks) {
        const float* zp = z + (size_t)(rbase + lo) * GD + g * ND + ks * 32 + hi * 8;
        float vv[8];
        *reinterpret_cast<float4*>(&vv[0]) = reinterpret_cast<const float4*>(zp)[0];
        *reinterpret_cast<float4*>(&vv[4]) = reinterpret_cast<const float4*>(zp)[1];
#pragma unroll
        for (int e = 0; e < 8; ++e) {
            short hs, ls;
            bsplit(vv[e], hs, ls);
            Ah[ks][e] = hs;
            Al[ks][e] = ls;
        }
    }

    // per-q streams: (best, b2, bk, k2) — round-3 numerics exactly
    float best[4], b2[4];
    int   bk[4], k2[4];
#pragma unroll
    for (int q = 0; q < 4; ++q) { best[q] = 3.0e38f; b2[q] = 3.0e38f; bk[q] = 0; k2[q] = 0; }

    const int laneoff = lo * 64 + hi * 8;   // shorts; code-row stride is 64 shorts

    // rotating 2-slot B-pair register buffer; pair p = ks*4 + n, slot = p&1
    short8 bh[2], bl[2];
    bh[0] = *reinterpret_cast<const short8*>(cbh + laneoff);          // (it0,p0)
    bl[0] = *reinterpret_cast<const short8*>(cbl + laneoff);
    bh[1] = *reinterpret_cast<const short8*>(cbh + 1024 + laneoff);   // (it0,p1)
    bl[1] = *reinterpret_cast<const short8*>(cbl + 1024 + laneoff);

#pragma unroll 1
    for (int it = 0; it < 16; ++it) {
        const int kb = it * 64;
        float c2v[4];
#pragma unroll
        for (int n = 0; n < 4; ++n) c2v[n] = c2g[kb + n * 16 + lo];

        f32x4 acc[4] = {{0.f,0.f,0.f,0.f},{0.f,0.f,0.f,0.f},{0.f,0.f,0.f,0.f},{0.f,0.f,0.f,0.f}};
#pragma unroll
        for (int p = 0; p < 8; ++p) {
            const int ks = p >> 2, n = p & 3;
            const int sl = p & 1;
            acc[n] = __builtin_amdgcn_mfma_f32_16x16x32_bf16(Ah[ks], bh[sl], acc[n], 0, 0, 0);
            acc[n] = __builtin_amdgcn_mfma_f32_16x16x32_bf16(Ah[ks], bl[sl], acc[n], 0, 0, 0);
            acc[n] = __builtin_amdgcn_mfma_f32_16x16x32_bf16(Al[ks], bh[sl], acc[n], 0, 0, 0);
            const int s = it * 8 + p + 2;            // prefetch pair s into freed slot
            if (s < 128) {
                const int itn = s >> 3, pn = s & 7;
                const size_t noff = (size_t)itn * 4096 + (size_t)(pn & 3) * 1024
                                  + (size_t)(pn >> 2) * 32 + laneoff;
                bh[sl] = *reinterpret_cast<const short8*>(cbh + noff);
                bl[sl] = *reinterpret_cast<const short8*>(cbl + noff);
            }
        }

        // epilogue: score = c2 - 2*zc (z2 constant per row); round-3 arithmetic
#pragma unroll
        for (int n = 0; n < 4; ++n) {
            const int kv = kb + n * 16 + lo;
#pragma unroll
            for (int q = 0; q < 4; ++q) {
                const float s = fmaf(-2.0f, acc[n][q], c2v[n]);
                const bool lt  = s < best[q];
                const bool lt2 = s < b2[q];
                b2[q]   = lt ? best[q] : (lt2 ? s : b2[q]);
                k2[q]   = lt ? bk[q]   : (lt2 ? kv : k2[q]);
                best[q] = lt ? s : best[q];
                bk[q]   = lt ? kv : bk[q];
            }
        }
    }

    // butterfly over the 16 lo-lanes (round-3 verbatim)
    f32x4* cand = (f32x4*)((char*)ws + WS_CAND_OFF);
#pragma unroll
    for (int q = 0; q < 4; ++q) {
        float pb = best[q], p2 = b2[q];
        int   kq = bk[q],   kq2 = k2[q];
#pragma unroll
        for (int st = 1; st < 16; st <<= 1) {
            const float ob  = __shfl_xor(pb, st);
            const int   obk = __shfl_xor(kq, st);
            const float ob2 = __shfl_xor(p2, st);
            const int   ok2 = __shfl_xor(kq2, st);
            const bool bet = (ob < pb) || (ob == pb && obk < kq);
            const float lb  = bet ? pb : ob;      // loser's best
            const int   lk  = bet ? kq : obk;
            const float wb2 = bet ? ob2 : p2;     // winner's second
            const int   wk2 = bet ? ok2 : kq2;
            const bool s2 = (lb < wb2) || (lb == wb2 && lk < wk2);
            p2  = s2 ? lb : wb2;
            kq2 = s2 ? lk : wk2;
            pb  = bet ? ob : pb;
            kq  = bet ? obk : kq;
        }

        if (lo == 0) {
            const int row = rbase + hi * 4 + q;
            f32x4 c;
            c[0] = pb;
            c[1] = __int_as_float(kq);
            c[2] = p2;
            c[3] = __int_as_float(kq2);
            cand[(size_t)g * NB + row] = c;
        }
    }
}

// ---------------- pick: window-2 exact rescue, write outputs ----------------
__global__ __launch_bounds__(256) void vq_pick(const float* __restrict__ z,
                                               const float* __restrict__ cb,
                                               float* __restrict__ out,
                                               float* __restrict__ ws) {
    const int tid  = threadIdx.x;
    const int wid  = tid >> 6;
    const int lane = tid & 63;
    const int unit = blockIdx.x * 4 + wid;     // 0..65535
    const int row  = unit >> 3;
    const int g    = unit & 7;

    const f32x4* cand = (const f32x4*)((const char*)ws + WS_CAND_OFF);
    const f32x4 cd = cand[(size_t)g * NB + row];
    const float bapp = cd[0];
    const int   bk   = __float_as_int(cd[1]);

    const float zd = z[(size_t)row * GD + g * ND + lane];
    int win = bk;

    if (cd[2] - bapp <= MARGIN) {              // wave-uniform rescue branch
        const int kalt = __float_as_int(cd[3]);
        const float* cgrp = cb + (size_t)g * NK * ND;
        const float* c2g  = (const float*)((const char*)ws + WS_C2_OFF) + g * NK;
        const float z2 = wredsum(zd * zd);
        const float c1 = cgrp[(size_t)bk * ND + lane];
        const float d1 = (z2 + c2g[bk]) - 2.0f * wredsum(zd * c1);
        const float c2 = cgrp[(size_t)kalt * ND + lane];
        const float d2 = (z2 + c2g[kalt]) - 2.0f * wredsum(zd * c2);
        if (d2 < d1 || (d2 == d1 && kalt < bk)) win = kalt;
    }

    const float cw = cb[((size_t)g * NK + win) * ND + lane];
    out[(size_t)row * GD + g * ND + lane] = zd + (cw - zd);

    const float e  = zd - cw;
    const float cs = wredsum(e * e);

    __shared__ float sh[4];
    if (lane == 0) {
        out[(size_t)NB * GD + (size_t)row * NG + g] = (float)win;
        atomicAdd((unsigned*)((char*)ws + WS_HIST_OFF) + win, 1u);
        sh[wid] = cs;
    }
    __syncthreads();
    if (tid == 0)
        ((float*)((char*)ws + WS_PART_OFF))[blockIdx.x] = (sh[0] + sh[1]) + (sh[2] + sh[3]);
}

// ---------------- finalize ----------------
__global__ __launch_bounds__(1024) void vq_final(const float* __restrict__ ws,
                                                 float* __restrict__ out) {
    const int t = threadIdx.x;
    __shared__ float se[1024];
    __shared__ float sc[1024];
    const unsigned cnt = ((const unsigned*)((const char*)ws + WS_HIST_OFF))[t];
    const float usage = (float)cnt * (1.0f / 65536.f);
    se[t] = -usage * logf(usage + 1e-10f);
    const float* part = (const float*)((const char*)ws + WS_PART_OFF);
    float s = 0.f;
#pragma unroll
    for (int i = 0; i < 16; ++i) s += part[t * 16 + i];
    sc[t] = s;
    __syncthreads();
    for (int st = 512; st > 0; st >>= 1) {
        if (t < st) {
            se[t] += se[t + st];
            sc[t] += sc[t + st];
        }
        __syncthreads();
    }
    if (t == 0) {
        float* scal = out + (size_t)NB * GD + (size_t)NB * NG;
        scal[0] = sc[0] * (1.0f / ((float)NB * NG * ND));  // commitment_loss
        scal[1] = 0.0f;                                    // codebook_loss
        scal[2] = se[0];                                   // entropy
        scal[3] = expf(se[0]);                             // perplexity
    }
}

extern "C" void kernel_launch(void* const* d_in, const int* in_sizes, int n_in,
                              void* d_out, int out_size, void* d_ws, size_t ws_size,
                              hipStream_t stream) {
    const float* z  = (const float*)d_in[0];
    const float* cb = (const float*)d_in[1];
    float* out = (float*)d_out;
    float* ws  = (float*)d_ws;

    hipLaunchKernelGGL(vq_prep,  dim3(32),     dim3(256),  0, stream, cb, ws);
    hipLaunchKernelGGL(vq_score, dim3(128, 8), dim3(256),  0, stream, z, ws);
    hipLaunchKernelGGL(vq_pick,  dim3(16384),  dim3(256),  0, stream, z, cb, out, ws);
    hipLaunchKernelGGL(vq_final, dim3(1),      dim3(1024), 0, stream, ws, out);
}

// Round 8
// 78.498 us; speedup vs baseline: 4.6614x; 2.0530x over previous
//
#include <hip/hip_runtime.h>
#include <hip/hip_bf16.h>
#include <math.h>

#define NB 8192
#define NG 8
#define NK 1024
#define ND 64
#define GD 512
#define MARGIN 2.5e-4f

typedef __attribute__((ext_vector_type(8))) short short8;
typedef __attribute__((ext_vector_type(4))) float f32x4;

// ws BYTE layout
#define WS_C2_OFF   0                          // f32[8192] exact c2, 32KB
#define WS_STG_OFF  32768                      // swizzled bf16 hi/lo staging, 8g*16it*16KB = 2MB
#define WS_CAND_OFF (32768 + 2097152)          // f32x4[65536], 1MB
#define WS_HIST_OFF (WS_CAND_OFF + 1048576)    // u32[1024]
#define WS_PART_OFF (WS_HIST_OFF + 4096)       // f32[16384]

typedef const __attribute__((address_space(1))) unsigned int glds_src_t;
typedef __attribute__((address_space(3))) unsigned int glds_dst_t;

__device__ inline void bsplit(float v, short& hs, short& ls) {
    __hip_bfloat16 h = __float2bfloat16(v);
    float hf = __bfloat162float(h);
    __hip_bfloat16 l = __float2bfloat16(v - hf);
    hs = *reinterpret_cast<short*>(&h);
    ls = *reinterpret_cast<short*>(&l);
}

__device__ inline float wredsum(float v) {
#pragma unroll
    for (int st = 1; st < 64; st <<= 1) v += __shfl_xor(v, st);
    return v;
}

// ---- prep: c2 exact; bf16 hi/lo codebook written as the XOR-swizzled staging image ----
// image: [g][it][hi-table 8KB | lo-table 8KB]; row r (code k&63) at r*128;
// logical 16B-granule j (d=8j..8j+7) stored at physical granule j^(r&7).
__global__ __launch_bounds__(256) void vq_prep(const float* __restrict__ cb,
                                               float* __restrict__ ws) {
    const int gid = blockIdx.x * 256 + threadIdx.x;   // code id 0..8191
    const int g  = gid >> 10, k = gid & 1023;
    const int it = k >> 6,   row = k & 63;
    const float* c = cb + (size_t)gid * ND;
    char* base = (char*)ws + WS_STG_OFF + (size_t)(g * 16 + it) * 16384 + row * 128;

    float a0 = 0.f, a1 = 0.f, a2 = 0.f, a3 = 0.f;
#pragma unroll
    for (int j = 0; j < 8; ++j) {                     // granule j: d = 8j..8j+7
        const float4 v0 = reinterpret_cast<const float4*>(c)[2 * j];
        const float4 v1 = reinterpret_cast<const float4*>(c)[2 * j + 1];
        a0 = fmaf(v0.x, v0.x, a0); a1 = fmaf(v0.y, v0.y, a1);
        a2 = fmaf(v0.z, v0.z, a2); a3 = fmaf(v0.w, v0.w, a3);
        a0 = fmaf(v1.x, v1.x, a0); a1 = fmaf(v1.y, v1.y, a1);
        a2 = fmaf(v1.z, v1.z, a2); a3 = fmaf(v1.w, v1.w, a3);
        short h0, l0, h1, l1, h2, l2, h3, l3;
        short h4, l4, h5, l5, h6, l6, h7, l7;
        bsplit(v0.x, h0, l0); bsplit(v0.y, h1, l1);
        bsplit(v0.z, h2, l2); bsplit(v0.w, h3, l3);
        bsplit(v1.x, h4, l4); bsplit(v1.y, h5, l5);
        bsplit(v1.z, h6, l6); bsplit(v1.w, h7, l7);
        short8 hs, ls;
        hs[0] = h0; hs[1] = h1; hs[2] = h2; hs[3] = h3;
        hs[4] = h4; hs[5] = h5; hs[6] = h6; hs[7] = h7;
        ls[0] = l0; ls[1] = l1; ls[2] = l2; ls[3] = l3;
        ls[4] = l4; ls[5] = l5; ls[6] = l6; ls[7] = l7;
        const int off = (j ^ (row & 7)) << 4;
        *reinterpret_cast<short8*>(base + off)        = hs;
        *reinterpret_cast<short8*>(base + 8192 + off) = ls;
    }
    ((float*)((char*)ws + WS_C2_OFF))[gid] = (a0 + a1) + (a2 + a3);
    if (gid < NK) ((unsigned*)((char*)ws + WS_HIST_OFF))[gid] = 0u;
}

// ---- score: 2-phase LDS double-buffer via global_load_lds; bit-identical r3 numerics ----
__global__ __launch_bounds__(256, 4) void vq_score(const float* __restrict__ z,
                                                   float* __restrict__ ws) {
    __shared__ __align__(16) char smem[2][16384];
    const int tid  = threadIdx.x;
    const int w    = tid >> 6;
    const int lane = tid & 63;
    const int lo   = lane & 15, hi = lane >> 4;
    const int g    = blockIdx.y;
    const int rbase = blockIdx.x * 64 + w * 16;

    const char*  stg = (const char*)ws + WS_STG_OFF + (size_t)g * 16 * 16384;
    const float* c2g = (const float*)((const char*)ws + WS_C2_OFF) + g * NK;

    // A fragments (16 z-rows), bf16 hi/lo split. row=lo, d=ks*32+hi*8+e
    short8 Ah[2], Al[2];
#pragma unroll
    for (int ks = 0; ks < 2; ++ks) {
        const float* zp = z + (size_t)(rbase + lo) * GD + g * ND + ks * 32 + hi * 8;
        float vv[8];
        *reinterpret_cast<float4*>(&vv[0]) = reinterpret_cast<const float4*>(zp)[0];
        *reinterpret_cast<float4*>(&vv[4]) = reinterpret_cast<const float4*>(zp)[1];
#pragma unroll
        for (int e = 0; e < 8; ++e) {
            short hs, ls;
            bsplit(vv[e], hs, ls);
            Ah[ks][e] = hs;
            Al[ks][e] = ls;
        }
    }

    float best[4], b2[4];
    int   bk[4], k2[4];
#pragma unroll
    for (int q = 0; q < 4; ++q) { best[q] = 3.0e38f; b2[q] = 3.0e38f; bk[q] = 0; k2[q] = 0; }

    // swizzled read offsets (row&7 == lo&7 since row = n*16+lo)
    const int rowoff = lo * 128;
    const int swz0 = (((0 * 4 + hi) ^ (lo & 7)) << 4);
    const int swz1 = (((1 * 4 + hi) ^ (lo & 7)) << 4);
    const int stage_off = w * 4096 + lane * 16;       // this wave's staging quarter

    // prologue: stage it=0 into buf 0
#pragma unroll
    for (int i = 0; i < 4; ++i)
        __builtin_amdgcn_global_load_lds(
            (glds_src_t*)(const void*)(stg + stage_off + i * 1024),
            (glds_dst_t*)(void*)(&smem[0][stage_off + i * 1024]), 16, 0, 0);
    __syncthreads();

#pragma unroll 1
    for (int it = 0; it < 16; ++it) {
        const int cur = it & 1;
        if (it < 15) {                                // stage it+1 into other buffer
            const char* src = stg + (size_t)(it + 1) * 16384 + stage_off;
#pragma unroll
            for (int i = 0; i < 4; ++i)
                __builtin_amdgcn_global_load_lds(
                    (glds_src_t*)(const void*)(src + i * 1024),
                    (glds_dst_t*)(void*)(&smem[cur ^ 1][stage_off + i * 1024]), 16, 0, 0);
        }

        const int kb = it * 64;
        float c2v[4];
#pragma unroll
        for (int n = 0; n < 4; ++n) c2v[n] = c2g[kb + n * 16 + lo];

        f32x4 acc[4] = {{0.f,0.f,0.f,0.f},{0.f,0.f,0.f,0.f},{0.f,0.f,0.f,0.f},{0.f,0.f,0.f,0.f}};
#pragma unroll
        for (int p = 0; p < 8; ++p) {
            const int ks = p >> 2, n = p & 3;
            const int off = n * 2048 + rowoff + (ks ? swz1 : swz0);
            const short8 bhv = *reinterpret_cast<const short8*>(&smem[cur][off]);
            const short8 blv = *reinterpret_cast<const short8*>(&smem[cur][8192 + off]);
            acc[n] = __builtin_amdgcn_mfma_f32_16x16x32_bf16(ks ? Ah[1] : Ah[0], bhv, acc[n], 0, 0, 0);
            acc[n] = __builtin_amdgcn_mfma_f32_16x16x32_bf16(ks ? Ah[1] : Ah[0], blv, acc[n], 0, 0, 0);
            acc[n] = __builtin_amdgcn_mfma_f32_16x16x32_bf16(ks ? Al[1] : Al[0], bhv, acc[n], 0, 0, 0);
        }

        // epilogue: score = c2 - 2*zc (z2 constant per row); round-3 arithmetic
#pragma unroll
        for (int n = 0; n < 4; ++n) {
            const int kv = kb + n * 16 + lo;
#pragma unroll
            for (int q = 0; q < 4; ++q) {
                const float s = fmaf(-2.0f, acc[n][q], c2v[n]);
                const bool lt  = s < best[q];
                const bool lt2 = s < b2[q];
                b2[q]   = lt ? best[q] : (lt2 ? s : b2[q]);
                k2[q]   = lt ? bk[q]   : (lt2 ? kv : k2[q]);
                best[q] = lt ? s : best[q];
                bk[q]   = lt ? kv : bk[q];
            }
        }
        __syncthreads();                              // drains staging (vmcnt0) + buffer reuse
    }

    // butterfly over the 16 lo-lanes (round-3 verbatim)
    f32x4* cand = (f32x4*)((char*)ws + WS_CAND_OFF);
#pragma unroll
    for (int q = 0; q < 4; ++q) {
        float pb = best[q], p2 = b2[q];
        int   kq = bk[q],   kq2 = k2[q];
#pragma unroll
        for (int st = 1; st < 16; st <<= 1) {
            const float ob  = __shfl_xor(pb, st);
            const int   obk = __shfl_xor(kq, st);
            const float ob2 = __shfl_xor(p2, st);
            const int   ok2 = __shfl_xor(kq2, st);
            const bool bet = (ob < pb) || (ob == pb && obk < kq);
            const float lb  = bet ? pb : ob;
            const int   lk  = bet ? kq : obk;
            const float wb2 = bet ? ob2 : p2;
            const int   wk2 = bet ? ok2 : kq2;
            const bool s2 = (lb < wb2) || (lb == wb2 && lk < wk2);
            p2  = s2 ? lb : wb2;
            kq2 = s2 ? lk : wk2;
            pb  = bet ? ob : pb;
            kq  = bet ? obk : kq;
        }
        if (lo == 0) {
            const int row = rbase + hi * 4 + q;
            f32x4 c;
            c[0] = pb;
            c[1] = __int_as_float(kq);
            c[2] = p2;
            c[3] = __int_as_float(kq2);
            cand[(size_t)g * NB + row] = c;
        }
    }
}

// ---------------- pick: window-2 exact rescue, write outputs ----------------
__global__ __launch_bounds__(256) void vq_pick(const float* __restrict__ z,
                                               const float* __restrict__ cb,
                                               float* __restrict__ out,
                                               float* __restrict__ ws) {
    const int tid  = threadIdx.x;
    const int wid  = tid >> 6;
    const int lane = tid & 63;
    const int unit = blockIdx.x * 4 + wid;     // 0..65535
    const int row  = unit >> 3;
    const int g    = unit & 7;

    const f32x4* cand = (const f32x4*)((const char*)ws + WS_CAND_OFF);
    const f32x4 cd = cand[(size_t)g * NB + row];
    const float bapp = cd[0];
    const int   bk   = __float_as_int(cd[1]);

    const float zd = z[(size_t)row * GD + g * ND + lane];
    int win = bk;

    if (cd[2] - bapp <= MARGIN) {              // wave-uniform rescue branch
        const int kalt = __float_as_int(cd[3]);
        const float* cgrp = cb + (size_t)g * NK * ND;
        const float* c2g  = (const float*)((const char*)ws + WS_C2_OFF) + g * NK;
        const float z2 = wredsum(zd * zd);
        const float c1 = cgrp[(size_t)bk * ND + lane];
        const float d1 = (z2 + c2g[bk]) - 2.0f * wredsum(zd * c1);
        const float c2 = cgrp[(size_t)kalt * ND + lane];
        const float d2 = (z2 + c2g[kalt]) - 2.0f * wredsum(zd * c2);
        if (d2 < d1 || (d2 == d1 && kalt < bk)) win = kalt;
    }

    const float cw = cb[((size_t)g * NK + win) * ND + lane];
    out[(size_t)row * GD + g * ND + lane] = zd + (cw - zd);

    const float e  = zd - cw;
    const float cs = wredsum(e * e);

    __shared__ float sh[4];
    if (lane == 0) {
        out[(size_t)NB * GD + (size_t)row * NG + g] = (float)win;
        atomicAdd((unsigned*)((char*)ws + WS_HIST_OFF) + win, 1u);
        sh[wid] = cs;
    }
    __syncthreads();
    if (tid == 0)
        ((float*)((char*)ws + WS_PART_OFF))[blockIdx.x] = (sh[0] + sh[1]) + (sh[2] + sh[3]);
}

// ---------------- finalize ----------------
__global__ __launch_bounds__(1024) void vq_final(const float* __restrict__ ws,
                                                 float* __restrict__ out) {
    const int t = threadIdx.x;
    __shared__ float se[1024];
    __shared__ float sc[1024];
    const unsigned cnt = ((const unsigned*)((const char*)ws + WS_HIST_OFF))[t];
    const float usage = (float)cnt * (1.0f / 65536.f);
    se[t] = -usage * logf(usage + 1e-10f);
    const float* part = (const float*)((const char*)ws + WS_PART_OFF);
    float s = 0.f;
#pragma unroll
    for (int i = 0; i < 16; ++i) s += part[t * 16 + i];
    sc[t] = s;
    __syncthreads();
    for (int st = 512; st > 0; st >>= 1) {
        if (t < st) {
            se[t] += se[t + st];
            sc[t] += sc[t + st];
        }
        __syncthreads();
    }
    if (t == 0) {
        float* scal = out + (size_t)NB * GD + (size_t)NB * NG;
        scal[0] = sc[0] * (1.0f / ((float)NB * NG * ND));  // commitment_loss
        scal[1] = 0.0f;                                    // codebook_loss
        scal[2] = se[0];                                   // entropy
        scal[3] = expf(se[0]);                             // perplexity
    }
}

extern "C" void kernel_launch(void* const* d_in, const int* in_sizes, int n_in,
                              void* d_out, int out_size, void* d_ws, size_t ws_size,
                              hipStream_t stream) {
    const float* z  = (const float*)d_in[0];
    const float* cb = (const float*)d_in[1];
    float* out = (float*)d_out;
    float* ws  = (float*)d_ws;

    hipLaunchKernelGGL(vq_prep,  dim3(32),     dim3(256),  0, stream, cb, ws);
    hipLaunchKernelGGL(vq_score, dim3(128, 8), dim3(256),  0, stream, z, ws);
    hipLaunchKernelGGL(vq_pick,  dim3(16384),  dim3(256),  0, stream, z, cb, out, ws);
    hipLaunchKernelGGL(vq_final, dim3(1),      dim3(1024), 0, stream, ws, out);
}